// Round 6
// baseline (89.329 us; speedup 1.0000x reference)
//
#include <hip/hip_runtime.h>

#define CHUNK 512
#define NBINS 32
#define NCLS  10
#define MPAD  12   // masks padded to 12 floats/voxel -> 48B stride, b128-aligned

__global__ __launch_bounds__(256) void dvh_main(
    const float* __restrict__ pred, const float* __restrict__ targ,
    const float* __restrict__ mask, float* __restrict__ gD, float* __restrict__ gN,
    int chunksTotal, int chunksPerN)
{
    __shared__ float sEp[CHUNK];           // 2 KB
    __shared__ float sEt[CHUNK];           // 2 KB
    __shared__ float ml[CHUNK * MPAD];     // 24 KB  -> 28 KB total

    const int tid = threadIdx.x;
    const int bg  = tid & 3;               // bin-group: bins 8*bg .. 8*bg+7
    const int vg  = tid >> 2;              // voxel-group 0..63

    const float Kb = __expf(8.f * (float)bg);
    float K[8];
    K[0] = Kb;
    K[1] = Kb * 2.71828182845904523536f;
    K[2] = Kb * 7.38905609893065022723f;
    K[3] = Kb * 20.0855369231876677409f;
    K[4] = Kb * 54.5981500331442390781f;
    K[5] = Kb * 148.413159102576603421f;
    K[6] = Kb * 403.428793492735122608f;
    K[7] = Kb * 1096.63315842845859927f;

    // count classes: bg -> {bg, bg+4, 8+bg(if bg<2)}
    const int   bgC  = (bg < 2) ? (bg + 8) : bg;
    const float selC = (bg < 2) ? 1.f : 0.f;

    float acc[8][NCLS];
    #pragma unroll
    for (int j = 0; j < 8; ++j)
        #pragma unroll
        for (int c = 0; c < NCLS; ++c) acc[j][c] = 0.f;
    float cnt[6] = {0.f, 0.f, 0.f, 0.f, 0.f, 0.f};

    for (int chunk = blockIdx.x; chunk < chunksTotal; chunk += gridDim.x) {
        const float n0f = (chunk < chunksPerN) ? 1.f : 0.f;
        const float n1f = 1.f - n0f;
        const float n0s = n0f * selC, n1s = n1f * selC;
        const size_t vbase = (size_t)chunk * CHUNK;

        // ---- stage doses: exp once per voxel ----
        {
            const float2* p2 = (const float2*)(pred + vbase);
            const float2* t2 = (const float2*)(targ + vbase);
            float2 p = p2[tid];
            float2 t = t2[tid];
            *(float2*)(&sEp[2*tid]) = make_float2(__expf(-32.f*p.x), __expf(-32.f*p.y));
            *(float2*)(&sEt[2*tid]) = make_float2(__expf(-32.f*t.x), __expf(-32.f*t.y));
        }
        // ---- stage masks (coalesced float4, repack to 12-float stride) ----
        {
            const float4* m4g = (const float4*)(mask + vbase * NCLS);
            #pragma unroll
            for (int k = 0; k < 5; ++k) {
                float4 mv = m4g[k * 256 + tid];
                int f   = (k * 256 + tid) * 4;
                int vl  = f / 10;
                int c   = f - vl * 10;             // even
                int f2  = f + 2;
                int vl2 = f2 / 10;
                int c2  = f2 - vl2 * 10;           // even
                *(float2*)(&ml[vl  * MPAD + c ]) = make_float2(mv.x, mv.y);
                *(float2*)(&ml[vl2 * MPAD + c2]) = make_float2(mv.z, mv.w);
            }
        }
        __syncthreads();

        // ---- compute: thread = (voxel-group vg, bin-group bg), 8 iters ----
        #pragma unroll 2
        for (int v = vg; v < CHUNK; v += 64) {
            float ep = sEp[v], et = sEt[v];
            float de = et - ep;
            const float4* m4 = (const float4*)(ml + v * MPAD);
            float4 m0 = m4[0], m1 = m4[1], m2v = m4[2];
            float mcA = ml[v * MPAD + bg];
            float mcB = ml[v * MPAD + bg + 4];
            float mcC = ml[v * MPAD + bgC];
            #pragma unroll
            for (int j = 0; j < 8; ++j) {
                float ap = fmaf(ep, K[j], 1.f);
                float at = fmaf(et, K[j], 1.f);
                float r  = __builtin_amdgcn_rcpf(ap * at);
                float sd = de * K[j] * r;   // sig_p - sig_t
                acc[j][0] = fmaf(sd, m0.x,  acc[j][0]);
                acc[j][1] = fmaf(sd, m0.y,  acc[j][1]);
                acc[j][2] = fmaf(sd, m0.z,  acc[j][2]);
                acc[j][3] = fmaf(sd, m0.w,  acc[j][3]);
                acc[j][4] = fmaf(sd, m1.x,  acc[j][4]);
                acc[j][5] = fmaf(sd, m1.y,  acc[j][5]);
                acc[j][6] = fmaf(sd, m1.z,  acc[j][6]);
                acc[j][7] = fmaf(sd, m1.w,  acc[j][7]);
                acc[j][8] = fmaf(sd, m2v.x, acc[j][8]);
                acc[j][9] = fmaf(sd, m2v.y, acc[j][9]);
            }
            cnt[0] = fmaf(n0f, mcA, cnt[0]);
            cnt[1] = fmaf(n1f, mcA, cnt[1]);
            cnt[2] = fmaf(n0f, mcB, cnt[2]);
            cnt[3] = fmaf(n1f, mcB, cnt[3]);
            cnt[4] = fmaf(n0s, mcC, cnt[4]);
            cnt[5] = fmaf(n1s, mcC, cnt[5]);
        }
        __syncthreads();
    }

    // ---- reduce across the 16 voxel-groups within each wave (same bg = lane&3) ----
    #pragma unroll
    for (int j = 0; j < 8; ++j)
        #pragma unroll
        for (int c = 0; c < NCLS; ++c) {
            float v = acc[j][c];
            v += __shfl_xor(v, 4, 64);
            v += __shfl_xor(v, 8, 64);
            v += __shfl_xor(v, 16, 64);
            v += __shfl_xor(v, 32, 64);
            acc[j][c] = v;
        }
    #pragma unroll
    for (int s = 0; s < 6; ++s) {
        float v = cnt[s];
        v += __shfl_xor(v, 4, 64);
        v += __shfl_xor(v, 8, 64);
        v += __shfl_xor(v, 16, 64);
        v += __shfl_xor(v, 32, 64);
        cnt[s] = v;
    }
    __syncthreads();

    float* red  = ml;                      // 4 waves * 4 bg * 80 = 1280 floats
    float* redN = ml + 1280;               // 4 waves * 4 bg * 6  = 96 floats
    const int w = tid >> 6;
    if ((tid & 63) < 4) {                  // lane = bg holds vg-reduced values
        #pragma unroll
        for (int j = 0; j < 8; ++j)
            #pragma unroll
            for (int c = 0; c < NCLS; ++c)
                red[((w * 4 + bg) * 8 + j) * NCLS + c] = acc[j][c];
        #pragma unroll
        for (int s = 0; s < 6; ++s) redN[(w * 4 + bg) * 6 + s] = cnt[s];
    }
    __syncthreads();

    for (int i = tid; i < NBINS * NCLS; i += 256) {
        int b = i / NCLS, c = i - b * NCLS;
        int bgi = b >> 3, j = b & 7;
        float s = 0.f;
        #pragma unroll
        for (int ww = 0; ww < 4; ++ww)
            s += red[((ww * 4 + bgi) * 8 + j) * NCLS + c];
        atomicAdd(&gD[i], s);
    }
    if (tid < 2 * NCLS) {
        int c = tid >> 1, n = tid & 1;
        int bgi, slot;
        if (c < 4)      { bgi = c;     slot = 0 + n; }
        else if (c < 8) { bgi = c - 4; slot = 2 + n; }
        else            { bgi = c - 8; slot = 4 + n; }
        float s = 0.f;
        #pragma unroll
        for (int ww = 0; ww < 4; ++ww)
            s += redN[(ww * 4 + bgi) * 6 + slot];
        atomicAdd(&gN[n * NCLS + c], s);
    }
}

__global__ __launch_bounds__(512) void dvh_final(
    const float* __restrict__ gD, const float* __restrict__ gN, float* __restrict__ out)
{
    __shared__ float red[512];
    int t = threadIdx.x;
    float v = 0.f;
    if (t < NBINS * NCLS) {
        int c = t % NCLS;
        float nv0 = gN[c] + 1.f;
        float nv1 = gN[NCLS + c] + 1.f;
        float w = 1.f / (nv0 * nv0) + 1.f / (nv1 * nv1);
        float d = gD[t];
        v = d * d * w;
    }
    red[t] = v;
    __syncthreads();
    for (int s = 256; s > 0; s >>= 1) {
        if (t < s) red[t] += red[t + s];
        __syncthreads();
    }
    if (t == 0) out[0] = red[0] * (1.f / 1280.f);
}

extern "C" void kernel_launch(void* const* d_in, const int* in_sizes, int n_in,
                              void* d_out, int out_size, void* d_ws, size_t ws_size,
                              hipStream_t stream) {
    const float* pred = (const float*)d_in[0];
    const float* targ = (const float*)d_in[1];
    const float* mask = (const float*)d_in[2];
    float* gD = (float*)d_ws;                       // 320 floats: Delta[bin][c]
    float* gN = (float*)((char*)d_ws + 2048);       // 20 floats: sum-mask[n][c]

    hipMemsetAsync(d_ws, 0, 4096, stream);

    int totalVox    = in_sizes[0];           // N*V = 4194304
    int chunksTotal = totalVox / CHUNK;      // 8192
    int chunksPerN  = chunksTotal / 2;       // 4096

    dvh_main<<<1024, 256, 0, stream>>>(pred, targ, mask, gD, gN, chunksTotal, chunksPerN);
    dvh_final<<<1, 512, 0, stream>>>(gD, gN, (float*)d_out);
}

// Round 7
// 89.232 us; speedup vs baseline: 1.0011x; 1.0011x over previous
//
#include <hip/hip_runtime.h>
#include <hip/hip_fp16.h>

#define CHUNK 512
#define NBINS 32
#define NCLS  10
#define MHSTRIDE 16   // __half per voxel: 10 classes + 6 pad -> 32B record

__device__ __forceinline__ float2 h2f(unsigned int u) {
    __half2 h = *(__half2*)&u;
    return __half22float2(h);
}

__global__ __launch_bounds__(256) void dvh_main(
    const float* __restrict__ pred, const float* __restrict__ targ,
    const float* __restrict__ mask, float* __restrict__ gD, float* __restrict__ gN,
    int chunksTotal, int chunksPerN)
{
    __shared__ float2 sE[CHUNK];               // (Ep, Et) per voxel, 4 KB
    __shared__ __half mlh[CHUNK * MHSTRIDE];   // f16 masks, 16 KB  -> 20 KB total

    const int tid = threadIdx.x;
    const int bg  = tid & 7;               // bin-group: bins 4*bg .. 4*bg+3
    const int vg  = tid >> 3;              // voxel-group 0..31

    const float Kb = __expf(4.f * (float)bg);
    float K[4];
    K[0] = Kb;
    K[1] = Kb * 2.71828182845904523536f;
    K[2] = Kb * 7.38905609893065022723f;
    K[3] = Kb * 20.0855369231876677409f;

    const float selB = (bg < 2) ? 1.f : 0.f;   // classes 8,9 counted by bg 0,1

    float acc[4][NCLS];
    #pragma unroll
    for (int j = 0; j < 4; ++j)
        #pragma unroll
        for (int c = 0; c < NCLS; ++c) acc[j][c] = 0.f;
    float cnt[4] = {0.f, 0.f, 0.f, 0.f};   // [cA|n0, cA|n1, cB|n0, cB|n1]

    for (int chunk = blockIdx.x; chunk < chunksTotal; chunk += gridDim.x) {
        const float n0f = (chunk < chunksPerN) ? 1.f : 0.f;
        const float n1f = 1.f - n0f;
        const float n0s = n0f * selB, n1s = n1f * selB;
        const size_t vbase = (size_t)chunk * CHUNK;

        // ---- stage doses: exp once per voxel, (Ep,Et) pairs ----
        {
            const float2* p2 = (const float2*)(pred + vbase);
            const float2* t2 = (const float2*)(targ + vbase);
            float2 p = p2[tid];
            float2 t = t2[tid];
            sE[2*tid]   = make_float2(__expf(-32.f*p.x), __expf(-32.f*t.x));
            sE[2*tid+1] = make_float2(__expf(-32.f*p.y), __expf(-32.f*t.y));
        }
        // ---- stage masks: coalesced float4, pack to f16 (exact for 0/1) ----
        {
            const float4* m4g = (const float4*)(mask + vbase * NCLS);
            #pragma unroll
            for (int k = 0; k < 5; ++k) {
                float4 mv = m4g[k * 256 + tid];
                int f   = (k * 256 + tid) * 4;
                int vl  = f / 10;
                int c   = f - vl * 10;             // even
                int f2  = f + 2;
                int vl2 = f2 / 10;
                int c2  = f2 - vl2 * 10;           // even
                *(__half2*)(&mlh[vl  * MHSTRIDE + c ]) = __floats2half2_rn(mv.x, mv.y);
                *(__half2*)(&mlh[vl2 * MHSTRIDE + c2]) = __floats2half2_rn(mv.z, mv.w);
            }
        }
        __syncthreads();

        // ---- compute: thread = (voxel-group vg, bin-group bg), 16 iters ----
        #pragma unroll 2
        for (int v = vg; v < CHUNK; v += 32) {
            float2 e  = sE[v];
            float  de = e.y - e.x;
            uint4 mu = *(const uint4*)(mlh + (size_t)v * MHSTRIDE);       // classes 0..7
            unsigned int u89 = *(const unsigned int*)(mlh + v * MHSTRIDE + 8); // classes 8,9
            float2 c01 = h2f(mu.x), c23 = h2f(mu.y);
            float2 c45 = h2f(mu.z), c67 = h2f(mu.w);
            float2 c89 = h2f(u89);
            float mcA = __half2float(mlh[v * MHSTRIDE + bg]);   // class bg (count)
            float mcB = (bg == 0) ? c89.x : c89.y;              // class 8/9 for bg 0/1
            #pragma unroll
            for (int j = 0; j < 4; ++j) {
                float ap = fmaf(e.x, K[j], 1.f);
                float at = fmaf(e.y, K[j], 1.f);
                float r  = __builtin_amdgcn_rcpf(ap * at);
                float sd = de * K[j] * r;   // sig_p - sig_t
                acc[j][0] = fmaf(sd, c01.x, acc[j][0]);
                acc[j][1] = fmaf(sd, c01.y, acc[j][1]);
                acc[j][2] = fmaf(sd, c23.x, acc[j][2]);
                acc[j][3] = fmaf(sd, c23.y, acc[j][3]);
                acc[j][4] = fmaf(sd, c45.x, acc[j][4]);
                acc[j][5] = fmaf(sd, c45.y, acc[j][5]);
                acc[j][6] = fmaf(sd, c67.x, acc[j][6]);
                acc[j][7] = fmaf(sd, c67.y, acc[j][7]);
                acc[j][8] = fmaf(sd, c89.x, acc[j][8]);
                acc[j][9] = fmaf(sd, c89.y, acc[j][9]);
            }
            cnt[0] = fmaf(n0f, mcA, cnt[0]);
            cnt[1] = fmaf(n1f, mcA, cnt[1]);
            cnt[2] = fmaf(n0s, mcB, cnt[2]);
            cnt[3] = fmaf(n1s, mcB, cnt[3]);
        }
        __syncthreads();
    }

    // ---- reduce across the 8 voxel-groups within each wave ----
    #pragma unroll
    for (int j = 0; j < 4; ++j)
        #pragma unroll
        for (int c = 0; c < NCLS; ++c) {
            float v = acc[j][c];
            v += __shfl_xor(v, 8, 64);
            v += __shfl_xor(v, 16, 64);
            v += __shfl_xor(v, 32, 64);
            acc[j][c] = v;
        }
    #pragma unroll
    for (int s = 0; s < 4; ++s) {
        float v = cnt[s];
        v += __shfl_xor(v, 8, 64);
        v += __shfl_xor(v, 16, 64);
        v += __shfl_xor(v, 32, 64);
        cnt[s] = v;
    }
    __syncthreads();

    float* red  = (float*)mlh;             // 4 waves * 8 bg * 40 = 1280 floats
    float* redN = ((float*)mlh) + 1280;    // 4 waves * 8 bg * 4  = 128 floats
    const int w = tid >> 6;
    if ((tid & 63) < 8) {                  // lane = bg holds vg-reduced values
        #pragma unroll
        for (int j = 0; j < 4; ++j)
            #pragma unroll
            for (int c = 0; c < NCLS; ++c)
                red[((w * 8 + bg) * 4 + j) * NCLS + c] = acc[j][c];
        #pragma unroll
        for (int s = 0; s < 4; ++s) redN[(w * 8 + bg) * 4 + s] = cnt[s];
    }
    __syncthreads();

    for (int i = tid; i < NBINS * NCLS; i += 256) {
        int b = i / NCLS, c = i - b * NCLS;
        int bgi = b >> 2, j = b & 3;
        float s = 0.f;
        #pragma unroll
        for (int ww = 0; ww < 4; ++ww)
            s += red[((ww * 8 + bgi) * 4 + j) * NCLS + c];
        atomicAdd(&gD[i], s);
    }
    if (tid < 2 * NCLS) {
        int c = tid >> 1, n = tid & 1;
        int bgi  = (c < 8) ? c : (c - 8);
        int slot = ((c < 8) ? 0 : 2) + n;
        float s = 0.f;
        #pragma unroll
        for (int ww = 0; ww < 4; ++ww)
            s += redN[(ww * 8 + bgi) * 4 + slot];
        atomicAdd(&gN[n * NCLS + c], s);
    }
}

__global__ __launch_bounds__(512) void dvh_final(
    const float* __restrict__ gD, const float* __restrict__ gN, float* __restrict__ out)
{
    __shared__ float red[512];
    int t = threadIdx.x;
    float v = 0.f;
    if (t < NBINS * NCLS) {
        int c = t % NCLS;
        float nv0 = gN[c] + 1.f;
        float nv1 = gN[NCLS + c] + 1.f;
        float w = 1.f / (nv0 * nv0) + 1.f / (nv1 * nv1);
        float d = gD[t];
        v = d * d * w;
    }
    red[t] = v;
    __syncthreads();
    for (int s = 256; s > 0; s >>= 1) {
        if (t < s) red[t] += red[t + s];
        __syncthreads();
    }
    if (t == 0) out[0] = red[0] * (1.f / 1280.f);
}

extern "C" void kernel_launch(void* const* d_in, const int* in_sizes, int n_in,
                              void* d_out, int out_size, void* d_ws, size_t ws_size,
                              hipStream_t stream) {
    const float* pred = (const float*)d_in[0];
    const float* targ = (const float*)d_in[1];
    const float* mask = (const float*)d_in[2];
    float* gD = (float*)d_ws;                       // 320 floats: Delta[bin][c]
    float* gN = (float*)((char*)d_ws + 2048);       // 20 floats: sum-mask[n][c]

    hipMemsetAsync(d_ws, 0, 4096, stream);

    int totalVox    = in_sizes[0];           // N*V = 4194304
    int chunksTotal = totalVox / CHUNK;      // 8192
    int chunksPerN  = chunksTotal / 2;       // 4096

    dvh_main<<<2048, 256, 0, stream>>>(pred, targ, mask, gD, gN, chunksTotal, chunksPerN);
    dvh_final<<<1, 512, 0, stream>>>(gD, gN, (float*)d_out);
}

// Round 8
// 81.341 us; speedup vs baseline: 1.0982x; 1.0970x over previous
//
#include <hip/hip_runtime.h>

typedef __attribute__((ext_vector_type(8))) short short8;   // 8 bf16 (4 VGPR)
typedef __attribute__((ext_vector_type(4))) float f32x4;    // MFMA C/D
typedef __attribute__((ext_vector_type(4))) int int4v;

#define CHUNK 512
#define NBINS 32
#define NCLS  10

__device__ __forceinline__ float asf(unsigned int u) { return __builtin_bit_cast(float, u); }
__device__ __forceinline__ unsigned int asu(float f) { return __builtin_bit_cast(unsigned int, f); }

__global__ __launch_bounds__(256) void dvh_main(
    const float* __restrict__ pred, const float* __restrict__ targ,
    const float* __restrict__ mask, float* __restrict__ gD, float* __restrict__ gN,
    int chunksTotal, int chunksPerN)
{
    __shared__ float2 sE[CHUNK];                 // (Ep,Et) per voxel, 4 KB
    __shared__ unsigned short mT[16 * 512];      // bf16 masks, transposed [cls][vox], swizzled, 16 KB

    const int tid  = threadIdx.x;
    const int lane = tid & 63;
    const int w    = tid >> 6;       // wave 0..3
    const int n15  = lane & 15;      // MFMA row/col index
    const int g    = lane >> 4;      // k-group 0..3

    const float K1 = __expf((float)n15);        // e^bin for bins 0..15
    const float K2 = K1 * 8886110.5f;           // * e^16 -> bins 16..31

    // zero junk class rows 10..15 (read by B-frags, never staged)
    for (int i = tid; i < 6 * 512; i += 256) mT[10 * 512 + i] = 0;

    // precompute the 20 swizzled LDS offsets for mask staging (tid-fixed)
    int soff[20];
    #pragma unroll
    for (int k = 0; k < 5; ++k) {
        int f = (k * 256 + tid) * 4;
        #pragma unroll
        for (int e = 0; e < 4; ++e) {
            int v = (f + e) / 10;
            int c = (f + e) - v * 10;
            soff[k * 4 + e] = c * 512 + (((v >> 3) ^ (c & 7)) << 3) + (v & 7);
        }
    }

    f32x4 accH1 = {0,0,0,0}, accL1 = {0,0,0,0};  // bins 0-15 hi/lo
    f32x4 accH2 = {0,0,0,0}, accL2 = {0,0,0,0};  // bins 16-31 hi/lo
    f32x4 cnt0  = {0,0,0,0}, cnt1  = {0,0,0,0};  // voxel counts per n
    short8 ones;
    #pragma unroll
    for (int i = 0; i < 8; ++i) ones[i] = (short)0x3F80;   // bf16 1.0

    for (int chunk = blockIdx.x; chunk < chunksTotal; chunk += gridDim.x) {
        const size_t vbase = (size_t)chunk * CHUNK;
        // ---- stage doses: exp once per voxel ----
        {
            float2 p = ((const float2*)(pred + vbase))[tid];
            float2 t = ((const float2*)(targ + vbase))[tid];
            *(float4*)&sE[2 * tid] = make_float4(__expf(-32.f * p.x), __expf(-32.f * t.x),
                                                 __expf(-32.f * p.y), __expf(-32.f * t.y));
        }
        // ---- stage masks: coalesced, 0/1 -> bf16 = top 16 bits, swizzled transpose ----
        {
            const uint4* m4g = (const uint4*)(mask + vbase * NCLS);
            #pragma unroll
            for (int k = 0; k < 5; ++k) {
                uint4 mv = m4g[k * 256 + tid];
                mT[soff[k * 4 + 0]] = (unsigned short)(mv.x >> 16);
                mT[soff[k * 4 + 1]] = (unsigned short)(mv.y >> 16);
                mT[soff[k * 4 + 2]] = (unsigned short)(mv.z >> 16);
                mT[soff[k * 4 + 3]] = (unsigned short)(mv.w >> 16);
            }
        }
        __syncthreads();

        const bool isN0 = (chunk < chunksPerN);
        #pragma unroll
        for (int st = 0; st < 4; ++st) {
            const int vb = (w * 4 + st) * 32;    // this wave's 32-voxel K-block
            const int v0 = vb + g * 8;           // this lane's 8 voxels
            // B fragment: mask[k=v0..v0+7][n=n15] (swizzled read matches staging)
            short8 fb = *(const short8*)&mT[n15 * 512 + (((v0 >> 3) ^ (n15 & 7)) << 3)];
            const float4* e4 = (const float4*)&sE[v0];   // (Ep,Et) pairs

            int uh1[4], ul1[4], uh2[4], ul2[4];
            #pragma unroll
            for (int j = 0; j < 4; ++j) {
                float4 q = e4[j];                 // vox a: (q.x,q.y)  vox b: (q.z,q.w)
                float dea = q.y - q.x, deb = q.w - q.z;
                // bin set 1 (K1)
                float pa = fmaf(q.x, K1, 1.f) * fmaf(q.y, K1, 1.f);
                float pb = fmaf(q.z, K1, 1.f) * fmaf(q.w, K1, 1.f);
                float sa = dea * K1 * __builtin_amdgcn_rcpf(pa);
                float sb = deb * K1 * __builtin_amdgcn_rcpf(pb);
                unsigned ua = asu(sa), ub = asu(sb);
                uh1[j] = (int)((ua >> 16) | (ub & 0xffff0000u));
                float la = sa - asf(ua & 0xffff0000u);
                float lb = sb - asf(ub & 0xffff0000u);
                unsigned lo1;
                asm("v_cvt_pk_bf16_f32 %0, %1, %2" : "=v"(lo1) : "v"(la), "v"(lb));
                ul1[j] = (int)lo1;
                // bin set 2 (K2)
                float pc = fmaf(q.x, K2, 1.f) * fmaf(q.y, K2, 1.f);
                float pd = fmaf(q.z, K2, 1.f) * fmaf(q.w, K2, 1.f);
                float sc = dea * K2 * __builtin_amdgcn_rcpf(pc);
                float sd = deb * K2 * __builtin_amdgcn_rcpf(pd);
                unsigned uc = asu(sc), ud = asu(sd);
                uh2[j] = (int)((uc >> 16) | (ud & 0xffff0000u));
                float lc = sc - asf(uc & 0xffff0000u);
                float ld = sd - asf(ud & 0xffff0000u);
                unsigned lo2;
                asm("v_cvt_pk_bf16_f32 %0, %1, %2" : "=v"(lo2) : "v"(lc), "v"(ld));
                ul2[j] = (int)lo2;
            }
            int4v th1 = {uh1[0], uh1[1], uh1[2], uh1[3]};
            int4v tl1 = {ul1[0], ul1[1], ul1[2], ul1[3]};
            int4v th2 = {uh2[0], uh2[1], uh2[2], uh2[3]};
            int4v tl2 = {ul2[0], ul2[1], ul2[2], ul2[3]};
            short8 A1h = __builtin_bit_cast(short8, th1);
            short8 A1l = __builtin_bit_cast(short8, tl1);
            short8 A2h = __builtin_bit_cast(short8, th2);
            short8 A2l = __builtin_bit_cast(short8, tl2);

            accH1 = __builtin_amdgcn_mfma_f32_16x16x32_bf16(A1h, fb, accH1, 0, 0, 0);
            accL1 = __builtin_amdgcn_mfma_f32_16x16x32_bf16(A1l, fb, accL1, 0, 0, 0);
            accH2 = __builtin_amdgcn_mfma_f32_16x16x32_bf16(A2h, fb, accH2, 0, 0, 0);
            accL2 = __builtin_amdgcn_mfma_f32_16x16x32_bf16(A2l, fb, accL2, 0, 0, 0);
            if (isN0) cnt0 = __builtin_amdgcn_mfma_f32_16x16x32_bf16(ones, fb, cnt0, 0, 0, 0);
            else      cnt1 = __builtin_amdgcn_mfma_f32_16x16x32_bf16(ones, fb, cnt1, 0, 0, 0);
        }
        __syncthreads();
    }

    // ---- epilogue: block reduce via LDS (reuse mT), then atomics ----
    __syncthreads();
    float* red  = (float*)mT;        // [4 waves][32 bins][10 cls] = 1280 floats
    float* redN = red + 1280;        // [4 waves][32] (n0: 0..9, n1: 16..25)

    f32x4 d1 = accH1 + accL1;
    f32x4 d2 = accH2 + accL2;
    if (n15 < NCLS) {
        #pragma unroll
        for (int r = 0; r < 4; ++r) {
            int b1 = g * 4 + r;                  // C/D: row=(lane>>4)*4+reg, col=lane&15
            red[(w * 32 + b1) * NCLS + n15]        = d1[r];
            red[(w * 32 + 16 + b1) * NCLS + n15]   = d2[r];
        }
    }
    if (lane < NCLS) {
        redN[w * 32 + lane]      = cnt0[0];      // row 0 of count tile
        redN[w * 32 + 16 + lane] = cnt1[0];
    }
    __syncthreads();

    for (int i = tid; i < NBINS * NCLS; i += 256) {
        float s = red[i] + red[320 + i] + red[640 + i] + red[960 + i];
        atomicAdd(&gD[i], s);
    }
    if (tid < 2 * NCLS) {
        int n = tid / NCLS, c = tid - n * NCLS;
        int o = n * 16 + c;
        float s = redN[o] + redN[32 + o] + redN[64 + o] + redN[96 + o];
        atomicAdd(&gN[n * NCLS + c], s);
    }
}

__global__ __launch_bounds__(512) void dvh_final(
    const float* __restrict__ gD, const float* __restrict__ gN, float* __restrict__ out)
{
    __shared__ float red[512];
    int t = threadIdx.x;
    float v = 0.f;
    if (t < NBINS * NCLS) {
        int c = t % NCLS;
        float nv0 = gN[c] + 1.f;
        float nv1 = gN[NCLS + c] + 1.f;
        float w = 1.f / (nv0 * nv0) + 1.f / (nv1 * nv1);
        float d = gD[t];
        v = d * d * w;
    }
    red[t] = v;
    __syncthreads();
    for (int s = 256; s > 0; s >>= 1) {
        if (t < s) red[t] += red[t + s];
        __syncthreads();
    }
    if (t == 0) out[0] = red[0] * (1.f / 1280.f);
}

extern "C" void kernel_launch(void* const* d_in, const int* in_sizes, int n_in,
                              void* d_out, int out_size, void* d_ws, size_t ws_size,
                              hipStream_t stream) {
    const float* pred = (const float*)d_in[0];
    const float* targ = (const float*)d_in[1];
    const float* mask = (const float*)d_in[2];
    float* gD = (float*)d_ws;                       // 320 floats: Delta[bin][cls]
    float* gN = (float*)((char*)d_ws + 2048);       // 20 floats: sum-mask[n][cls]

    hipMemsetAsync(d_ws, 0, 4096, stream);

    int totalVox    = in_sizes[0];           // N*V = 4194304
    int chunksTotal = totalVox / CHUNK;      // 8192
    int chunksPerN  = chunksTotal / 2;       // 4096

    dvh_main<<<2048, 256, 0, stream>>>(pred, targ, mask, gD, gN, chunksTotal, chunksPerN);
    dvh_final<<<1, 512, 0, stream>>>(gD, gN, (float*)d_out);
}

// Round 9
// 59.829 us; speedup vs baseline: 1.4931x; 1.3596x over previous
//
#include <hip/hip_runtime.h>

typedef __attribute__((ext_vector_type(8))) short short8;   // 8 bf16 (4 VGPR)
typedef __attribute__((ext_vector_type(4))) float f32x4;    // MFMA C/D
typedef __attribute__((ext_vector_type(4))) int int4v;

#define CHUNK 512
#define NBINS 32
#define NCLS  10
#define NREP  8

__device__ __forceinline__ float asf(unsigned int u) { return __builtin_bit_cast(float, u); }
__device__ __forceinline__ unsigned int asu(float f) { return __builtin_bit_cast(unsigned int, f); }

__global__ __launch_bounds__(256) void dvh_main(
    const float* __restrict__ pred, const float* __restrict__ targ,
    const float* __restrict__ mask, float* __restrict__ gD, float* __restrict__ gN,
    int chunksPerN)
{
    __shared__ float2 sE[CHUNK];                 // (Ep,Et) per voxel, 4 KB
    __shared__ unsigned short mT[16 * 512];      // bf16 masks [cls][vox] swizzled, 16 KB

    const int tid  = threadIdx.x;
    const int lane = tid & 63;
    const int w    = tid >> 6;       // wave 0..3
    const int n15  = lane & 15;      // MFMA row/col index
    const int g    = lane >> 4;      // k-group 0..3

    const int chunk = blockIdx.x;
    const size_t vbase = (size_t)chunk * CHUNK;

    // ---- issue ALL global loads first (latency hides under setup/zeroing) ----
    float2 p = ((const float2*)(pred + vbase))[tid];
    float2 t = ((const float2*)(targ + vbase))[tid];
    uint4 mv[5];
    {
        const uint4* m4g = (const uint4*)(mask + vbase * NCLS);
        #pragma unroll
        for (int k = 0; k < 5; ++k) mv[k] = m4g[k * 256 + tid];
    }

    // zero junk class rows 10..15 (read by B-frags, never staged)
    #pragma unroll
    for (int i = 0; i < 12; ++i) mT[10 * 512 + i * 256 + tid] = 0;

    const float K1 = __expf((float)n15);        // e^bin, bins 0..15
    const float K2 = K1 * 8886110.5f;           // * e^16 -> bins 16..31

    // ---- stage doses: exp once per voxel ----
    *(float4*)&sE[2 * tid] = make_float4(__expf(-32.f * p.x), __expf(-32.f * t.x),
                                         __expf(-32.f * p.y), __expf(-32.f * t.y));
    // ---- stage masks: 0/1 f32 -> bf16 (top 16 bits), swizzled transpose ----
    #pragma unroll
    for (int k = 0; k < 5; ++k) {
        int f = (k * 256 + tid) * 4;
        unsigned int e[4] = {mv[k].x, mv[k].y, mv[k].z, mv[k].w};
        #pragma unroll
        for (int q = 0; q < 4; ++q) {
            int v = (f + q) / 10;
            int c = (f + q) - v * 10;
            mT[c * 512 + (((v >> 3) ^ (c & 7)) << 3) + (v & 7)] =
                (unsigned short)(e[q] >> 16);
        }
    }
    __syncthreads();

    f32x4 accH1 = {0,0,0,0}, accL1 = {0,0,0,0};  // bins 0-15 hi/lo
    f32x4 accH2 = {0,0,0,0}, accL2 = {0,0,0,0};  // bins 16-31 hi/lo
    f32x4 cnt   = {0,0,0,0};                     // voxel counts
    short8 ones;
    #pragma unroll
    for (int i = 0; i < 8; ++i) ones[i] = (short)0x3F80;   // bf16 1.0

    #pragma unroll
    for (int st = 0; st < 4; ++st) {
        const int vb = (w * 4 + st) * 32;    // this wave's 32-voxel K-block
        const int v0 = vb + g * 8;           // this lane's 8 voxels
        short8 fb = *(const short8*)&mT[n15 * 512 + (((v0 >> 3) ^ (n15 & 7)) << 3)];
        const float4* e4 = (const float4*)&sE[v0];

        int uh1[4], ul1[4], uh2[4], ul2[4];
        #pragma unroll
        for (int j = 0; j < 4; ++j) {
            float4 q = e4[j];                 // vox a: (q.x,q.y)  vox b: (q.z,q.w)
            float dea = q.y - q.x, deb = q.w - q.z;
            float pa = fmaf(q.x, K1, 1.f) * fmaf(q.y, K1, 1.f);
            float pb = fmaf(q.z, K1, 1.f) * fmaf(q.w, K1, 1.f);
            float sa = dea * K1 * __builtin_amdgcn_rcpf(pa);
            float sb = deb * K1 * __builtin_amdgcn_rcpf(pb);
            unsigned ua = asu(sa), ub = asu(sb);
            uh1[j] = (int)((ua >> 16) | (ub & 0xffff0000u));
            float la = sa - asf(ua & 0xffff0000u);
            float lb = sb - asf(ub & 0xffff0000u);
            unsigned lo1;
            asm("v_cvt_pk_bf16_f32 %0, %1, %2" : "=v"(lo1) : "v"(la), "v"(lb));
            ul1[j] = (int)lo1;
            float pc = fmaf(q.x, K2, 1.f) * fmaf(q.y, K2, 1.f);
            float pd = fmaf(q.z, K2, 1.f) * fmaf(q.w, K2, 1.f);
            float sc = dea * K2 * __builtin_amdgcn_rcpf(pc);
            float sd = deb * K2 * __builtin_amdgcn_rcpf(pd);
            unsigned uc = asu(sc), ud = asu(sd);
            uh2[j] = (int)((uc >> 16) | (ud & 0xffff0000u));
            float lc = sc - asf(uc & 0xffff0000u);
            float ld = sd - asf(ud & 0xffff0000u);
            unsigned lo2;
            asm("v_cvt_pk_bf16_f32 %0, %1, %2" : "=v"(lo2) : "v"(lc), "v"(ld));
            ul2[j] = (int)lo2;
        }
        int4v th1 = {uh1[0], uh1[1], uh1[2], uh1[3]};
        int4v tl1 = {ul1[0], ul1[1], ul1[2], ul1[3]};
        int4v th2 = {uh2[0], uh2[1], uh2[2], uh2[3]};
        int4v tl2 = {ul2[0], ul2[1], ul2[2], ul2[3]};
        short8 A1h = __builtin_bit_cast(short8, th1);
        short8 A1l = __builtin_bit_cast(short8, tl1);
        short8 A2h = __builtin_bit_cast(short8, th2);
        short8 A2l = __builtin_bit_cast(short8, tl2);

        accH1 = __builtin_amdgcn_mfma_f32_16x16x32_bf16(A1h, fb, accH1, 0, 0, 0);
        accL1 = __builtin_amdgcn_mfma_f32_16x16x32_bf16(A1l, fb, accL1, 0, 0, 0);
        accH2 = __builtin_amdgcn_mfma_f32_16x16x32_bf16(A2h, fb, accH2, 0, 0, 0);
        accL2 = __builtin_amdgcn_mfma_f32_16x16x32_bf16(A2l, fb, accL2, 0, 0, 0);
        cnt   = __builtin_amdgcn_mfma_f32_16x16x32_bf16(ones, fb, cnt,   0, 0, 0);
    }
    __syncthreads();                  // all waves done reading mT

    // ---- epilogue: block reduce via LDS (reuse mT), then replicated atomics ----
    float* red  = (float*)mT;        // [4 waves][32 bins][10 cls] = 1280 floats
    float* redN = red + 1280;        // [4 waves][10]

    f32x4 d1 = accH1 + accL1;
    f32x4 d2 = accH2 + accL2;
    if (n15 < NCLS) {
        #pragma unroll
        for (int r = 0; r < 4; ++r) {
            int b1 = g * 4 + r;                  // C/D: row=(lane>>4)*4+reg, col=lane&15
            red[(w * 32 + b1) * NCLS + n15]      = d1[r];
            red[(w * 32 + 16 + b1) * NCLS + n15] = d2[r];
        }
    }
    if (lane < NCLS) redN[w * NCLS + lane] = cnt[0];   // row 0 of count tile
    __syncthreads();

    const int rep = chunk & (NREP - 1);
    float* gDr = gD + rep * (NBINS * NCLS);
    float* gNr = gN + rep * (2 * NCLS);
    const int nsel = (chunk < chunksPerN) ? 0 : 1;

    for (int i = tid; i < NBINS * NCLS; i += 256) {
        float s = red[i] + red[320 + i] + red[640 + i] + red[960 + i];
        atomicAdd(&gDr[i], s);
    }
    if (tid < NCLS) {
        float s = redN[tid] + redN[10 + tid] + redN[20 + tid] + redN[30 + tid];
        atomicAdd(&gNr[nsel * NCLS + tid], s);
    }
}

__global__ __launch_bounds__(512) void dvh_final(
    const float* __restrict__ gD, const float* __restrict__ gN, float* __restrict__ out)
{
    __shared__ float red[512];
    int t = threadIdx.x;
    float v = 0.f;
    if (t < NBINS * NCLS) {
        int c = t % NCLS;
        float nv0 = 1.f, nv1 = 1.f, d = 0.f;
        #pragma unroll
        for (int r = 0; r < NREP; ++r) {
            d   += gD[r * (NBINS * NCLS) + t];
            nv0 += gN[r * (2 * NCLS) + c];
            nv1 += gN[r * (2 * NCLS) + NCLS + c];
        }
        float w = 1.f / (nv0 * nv0) + 1.f / (nv1 * nv1);
        v = d * d * w;
    }
    red[t] = v;
    __syncthreads();
    for (int s = 256; s > 0; s >>= 1) {
        if (t < s) red[t] += red[t + s];
        __syncthreads();
    }
    if (t == 0) out[0] = red[0] * (1.f / 1280.f);
}

extern "C" void kernel_launch(void* const* d_in, const int* in_sizes, int n_in,
                              void* d_out, int out_size, void* d_ws, size_t ws_size,
                              hipStream_t stream) {
    const float* pred = (const float*)d_in[0];
    const float* targ = (const float*)d_in[1];
    const float* mask = (const float*)d_in[2];
    float* gD = (float*)d_ws;                            // NREP x 320 floats
    float* gN = (float*)((char*)d_ws + NREP * 320 * 4);  // NREP x 20 floats

    hipMemsetAsync(d_ws, 0, NREP * (320 + 20) * 4, stream);

    int totalVox    = in_sizes[0];           // N*V = 4194304
    int chunksTotal = totalVox / CHUNK;      // 8192
    int chunksPerN  = chunksTotal / 2;       // 4096

    dvh_main<<<chunksTotal, 256, 0, stream>>>(pred, targ, mask, gD, gN, chunksPerN);
    dvh_final<<<1, 512, 0, stream>>>(gD, gN, (float*)d_out);
}